// Round 7
// baseline (1469.988 us; speedup 1.0000x reference)
//
#include <hip/hip_runtime.h>

// ImageCaptionModel: B=128 T=32 V=10000 H=512 E=512 F=2048 NM=512
// Round 7: fence-free persistent recurrence, hardened.
//   - NO wbl2 / NO inv anywhere: cross-block data (h0/h1 bufs, H1all) moves via
//     relaxed agent-scope (sc1) loads/stores served at LLC; weights/Zx/bias are
//     read-only cached (stay WARM in per-XCD L2 across all 32 steps).
//   - flags: relaxed fetch_add / relaxed spin; vmcnt(0) before each signal.
//   - LDS only 16KB (logits tiles) -> >=2 blocks/CU capacity -> all 256 blocks
//     co-resident with margin (no staging, no 128KB-LDS deadlock risk).
//   blocks  0..31 : stepB (layer1), jt=bid, W1 from L2 (warm)
//   blocks 32..63 : stepA (layer0), jt=bid-32, W0h from L2 (warm)
//   blocks 64..255: logits workers, tiles gated on flagB[t]

typedef short s8v __attribute__((ext_vector_type(8)));   // 8 x bf16 bits
typedef float f4v __attribute__((ext_vector_type(4)));   // MFMA acc
typedef unsigned long long u64;

__device__ __forceinline__ unsigned short f2bf(float f) {
  unsigned u = __float_as_uint(f);
  u += 0x7fffu + ((u >> 16) & 1u);          // round-to-nearest-even
  return (unsigned short)(u >> 16);
}
__device__ __forceinline__ float sigm(float x) { return 1.0f / (1.0f + __expf(-x)); }
__device__ __forceinline__ float tanh_(float x) { return 1.0f - 2.0f / (1.0f + __expf(2.0f * x)); }

__device__ __forceinline__ void glds16(const unsigned short* g, unsigned short* l) {
  __builtin_amdgcn_global_load_lds((const __attribute__((address_space(1))) void*)g,
                                   (__attribute__((address_space(3))) void*)l, 16, 0, 0);
}

// LLC-coherent 16B load (2x relaxed agent-scope 8B atomic loads -> bypass L2)
__device__ __forceinline__ s8v ldA16(const unsigned short* p) {
  union { u64 q[2]; s8v v; } u;
  u.q[0] = __hip_atomic_load((const u64*)p,     __ATOMIC_RELAXED, __HIP_MEMORY_SCOPE_AGENT);
  u.q[1] = __hip_atomic_load((const u64*)p + 1, __ATOMIC_RELAXED, __HIP_MEMORY_SCOPE_AGENT);
  return u.v;
}
// LLC-coherent 2B store (relaxed agent-scope; plain short store w/ sc bits)
__device__ __forceinline__ void stU16(unsigned short* p, unsigned short v) {
  __hip_atomic_store(p, v, __ATOMIC_RELAXED, __HIP_MEMORY_SCOPE_AGENT);
}

// flags padded to 64B stride. FLAG(t)=stepA(t) done-count, FLAG(32+t)=stepB(t).
#define FLAG(i) flags[(i) * 16]

__device__ __forceinline__ void wait_ge(int* f, int n) {
  if (threadIdx.x == 0) {
    while (__hip_atomic_load(f, __ATOMIC_RELAXED, __HIP_MEMORY_SCOPE_AGENT) < n)
      __builtin_amdgcn_s_sleep(2);
  }
  __syncthreads();   // order: data loads below issue after the flag is seen
}
__device__ __forceinline__ void signal_inc(int* f) {
  asm volatile("s_waitcnt vmcnt(0)" ::: "memory");  // this wave's sc1 stores at LLC
  __syncthreads();                                  // all waves drained
  if (threadIdx.x == 0)
    __hip_atomic_fetch_add(f, 1, __ATOMIC_RELAXED, __HIP_MEMORY_SCOPE_AGENT);
}

// ---- fused pre-work: 6 transposes + cnn cvt + emb gather + state init + flags
__global__ void k_prep(const float* __restrict__ W_in, const float* __restrict__ W0,
                       const float* __restrict__ W1, const float* __restrict__ W_out,
                       const float* __restrict__ cnn, const float* __restrict__ emb,
                       const int* __restrict__ tok, const float* __restrict__ chs,
                       unsigned short* __restrict__ Win_t, unsigned short* __restrict__ W0e_t,
                       unsigned short* __restrict__ W0m_t, unsigned short* __restrict__ W0h_t,
                       unsigned short* __restrict__ W1_t, unsigned short* __restrict__ Wout_t,
                       unsigned short* __restrict__ cnn_b, unsigned short* __restrict__ Xe,
                       unsigned short* __restrict__ h0b1, unsigned short* __restrict__ h1b1,
                       float* __restrict__ h0f, float* __restrict__ c0f,
                       float* __restrict__ h1f, float* __restrict__ c1f,
                       int* __restrict__ flags) {
  int blk = blockIdx.x;
  if (blk < 11152) {   // transpose jobs
    const float* src; unsigned short* dst; int R, C, bx, by;
    if (blk < 1024)      { src = W_in;             dst = Win_t;  R = 2048; C = 512;   bx = blk & 15; by = blk >> 4; }
    else if (blk < 2048) { int b2 = blk - 1024; src = W0;              dst = W0e_t;  R = 512;  C = 2048;  bx = b2 & 63; by = b2 >> 6; }
    else if (blk < 3072) { int b2 = blk - 2048; src = W0 + 512 * 2048; dst = W0m_t;  R = 512;  C = 2048;  bx = b2 & 63; by = b2 >> 6; }
    else if (blk < 4096) { int b2 = blk - 3072; src = W0 + 1024 * 2048; dst = W0h_t; R = 512;  C = 2048;  bx = b2 & 63; by = b2 >> 6; }
    else if (blk < 6144) { int b2 = blk - 4096; src = W1;              dst = W1_t;   R = 1024; C = 2048;  bx = b2 & 63; by = b2 >> 6; }
    else                 { int b2 = blk - 6144; src = W_out;           dst = Wout_t; R = 512;  C = 10000; bx = b2 % 313; by = b2 / 313; }
    __shared__ float tile[32][33];
    int c0 = bx * 32, r0 = by * 32;
    int tx = threadIdx.x, ty = threadIdx.y;
#pragma unroll
    for (int i = 0; i < 4; i++) {
      int r = r0 + ty + i * 8, c = c0 + tx;
      if (r < R && c < C) tile[ty + i * 8][tx] = src[(size_t)r * C + c];
    }
    __syncthreads();
#pragma unroll
    for (int i = 0; i < 4; i++) {
      int c = c0 + ty + i * 8, r = r0 + tx;
      if (r < R && c < C) dst[(size_t)c * R + r] = f2bf(tile[tx][ty + i * 8]);
    }
    return;
  }
  int ft = threadIdx.y * 32 + threadIdx.x;
  if (blk < 11408) {        // cnn fp32 -> bf16 (65536 float4s)
    int i = (blk - 11152) * 256 + ft;
    float4 v = ((const float4*)cnn)[i];
    ushort4 p; p.x = f2bf(v.x); p.y = f2bf(v.y); p.z = f2bf(v.z); p.w = f2bf(v.w);
    ((ushort4*)cnn_b)[i] = p;
  } else if (blk < 13456) { // embedding gather (524288 float4s)
    int i = (blk - 11408) * 256 + ft;
    int r = i >> 7, k4 = (i & 127) * 4;
    int b = r & 127, t = r >> 7;
    int tk = tok[b * 32 + t];
    float4 v = *(const float4*)(emb + (size_t)tk * 512 + k4);
    ushort4 p; p.x = f2bf(v.x); p.y = f2bf(v.y); p.z = f2bf(v.z); p.w = f2bf(v.w);
    ((ushort4*)Xe)[i] = p;
  } else if (blk < 13712) { // init h/c state (65536)
    int i = (blk - 13456) * 256 + ft;
    int b = i >> 9, jj = i & 511;
    float h0 = chs[b * 1024 + jj], c0v = chs[b * 1024 + 512 + jj];
    float h1 = chs[131072 + b * 1024 + jj], c1v = chs[131072 + b * 1024 + 512 + jj];
    h0f[i] = h0; c0f[i] = c0v; h1f[i] = h1; c1f[i] = c1v;
    h0b1[i] = f2bf(h0); h1b1[i] = f2bf(h1);
  } else {                  // zero sync flags (1024 padded ints)
    for (int z = ft; z < 1024; z += 256) flags[z] = 0;
  }
}

// ---- generic 128x128-tile GEMM (pre-work): C = A[M][K] * Bt[N][K]^T (+epilogue)
// MODE 0: proc = leaky(acc+bias) -> outB ; MODE 1: Cf = acc+bias -> outF
// MODE 2: Zx = acc + add128[m&127][n] -> outF
template <int MODE>
__global__ __launch_bounds__(256, 2)
void k_gemm(const unsigned short* __restrict__ A, const unsigned short* __restrict__ Bt,
            const float* __restrict__ bias, const float* __restrict__ add128,
            float* __restrict__ outF, unsigned short* __restrict__ outB,
            int M, int N, int K) {
  __shared__ unsigned short As[4096];
  __shared__ unsigned short Bs[4096];
  int tid = threadIdx.x;
  int wave = tid >> 6, lane = tid & 63;
  int lr = lane & 15, lq = lane >> 4;
  int wm = (wave >> 1) * 64, wn = (wave & 1) * 64;
  int m0 = blockIdx.y * 128, n0 = blockIdx.x * 128;

  f4v acc[4][4];
  f4v zero = {0.0f, 0.0f, 0.0f, 0.0f};
#pragma unroll
  for (int i = 0; i < 4; i++)
#pragma unroll
    for (int j = 0; j < 4; j++) acc[i][j] = zero;

  int srow = tid >> 2, sofs = (tid & 3) * 8;
  int ar0 = m0 + srow, ar1 = ar0 + 64;
  int br0 = n0 + srow, br1 = br0 + 64;
  if (br0 >= N) br0 = N - 1;
  if (br1 >= N) br1 = N - 1;
  const unsigned short* Ag0 = A + (size_t)ar0 * K + sofs;
  const unsigned short* Ag1 = A + (size_t)ar1 * K + sofs;
  const unsigned short* Bg0 = Bt + (size_t)br0 * K + sofs;
  const unsigned short* Bg1 = Bt + (size_t)br1 * K + sofs;

  for (int k0 = 0; k0 < K; k0 += 32) {
    glds16(Ag0 + k0, &As[tid * 8]);
    glds16(Ag1 + k0, &As[2048 + tid * 8]);
    glds16(Bg0 + k0, &Bs[tid * 8]);
    glds16(Bg1 + k0, &Bs[2048 + tid * 8]);
    __syncthreads();
    s8v af[4], bfr[4];
#pragma unroll
    for (int i = 0; i < 4; i++) af[i] = *(const s8v*)&As[(wm + i * 16 + lr) * 32 + lq * 8];
#pragma unroll
    for (int i = 0; i < 4; i++) bfr[i] = *(const s8v*)&Bs[(wn + i * 16 + lr) * 32 + lq * 8];
#pragma unroll
    for (int i = 0; i < 4; i++)
#pragma unroll
      for (int j = 0; j < 4; j++)
        acc[i][j] = __builtin_amdgcn_mfma_f32_16x16x32_bf16(af[i], bfr[j], acc[i][j], 0, 0, 0);
    __syncthreads();
  }

#pragma unroll
  for (int i = 0; i < 4; i++) {
#pragma unroll
    for (int j = 0; j < 4; j++) {
      int nn = n0 + wn + j * 16 + lr;
      if (nn >= N) continue;
#pragma unroll
      for (int r = 0; r < 4; r++) {
        int mm = m0 + wm + i * 16 + lq * 4 + r;
        float v = acc[i][j][r];
        if (MODE == 0) {
          v += bias[nn];
          v = v > 0.0f ? v : 0.01f * v;
          outB[(size_t)mm * N + nn] = f2bf(v);
        } else if (MODE == 1) {
          v += bias[nn];
          outF[(size_t)mm * N + nn] = v;
        } else {
          v += add128[(size_t)(mm & 127) * N + nn];
          outF[(size_t)mm * N + nn] = v;
        }
      }
    }
  }
}

// ---- persistent recurrence + logits, fence-free ----
__global__ __launch_bounds__(256, 1)
void k_persist(const unsigned short* __restrict__ W0h_t, const unsigned short* __restrict__ W1_t,
               const float* __restrict__ Zx, const float* __restrict__ b1,
               unsigned short* __restrict__ h0b0, unsigned short* __restrict__ h0b1,
               unsigned short* __restrict__ h1b0, unsigned short* __restrict__ h1b1,
               float* __restrict__ h0f, float* __restrict__ c0f,
               float* __restrict__ h1f, float* __restrict__ c1f,
               unsigned short* __restrict__ H1all,
               const unsigned short* __restrict__ Wout_t, const float* __restrict__ b_out,
               float* __restrict__ out, int* __restrict__ flags) {
  __shared__ __align__(16) unsigned short As[4096];  // logits tiles only (16 KB)
  __shared__ __align__(16) unsigned short Bs[4096];
  int bid = blockIdx.x;
  int tid = threadIdx.x, wave = tid >> 6, lane = tid & 63;
  int lr = lane & 15, lq = lane >> 4, lqo = lq * 8;
  int rb0 = wave * 32 + lr;
  f4v zero = {0.0f, 0.0f, 0.0f, 0.0f};

  if (bid < 32) {
    // ======== stepB: z1 = [h0n(t)|h1(t-1)] @ W1 + b1 ; W1 slice warm in L2 ====
    int jt = bid;
    int j = jt * 16 + lr;
    const unsigned short* wb = W1_t + (size_t)j * 1024 + lqo;   // gate g: +g*524288
    float bi = b1[j], bo = b1[512 + j], bff = b1[1024 + j], bc = b1[1536 + j];
    for (int t = 0; t < 32; t++) {
      wait_ge(&FLAG(t), 32);                        // h0n(t) ready
      if (t >= 1) wait_ge(&FLAG(32 + t - 1), 32);   // h1(t-1) ready + WAR
      const unsigned short* h0r = (t & 1) ? h0b1 : h0b0;
      const unsigned short* h1r = (t & 1) ? h1b0 : h1b1;
      unsigned short* h1w = (t & 1) ? h1b1 : h1b0;
      f4v acc[2][4];
#pragma unroll
      for (int i = 0; i < 2; i++)
#pragma unroll
        for (int g = 0; g < 4; g++) acc[i][g] = zero;
      s8v a_s[8][2];    // depth-8 A ring (sc1 LLC loads)
      s8v b_s[4][4];    // depth-3-ahead B ring (L2-warm cached loads)
      auto issueA = [&](int kc) {
        int kcl = kc < 32 ? kc : 31;
        int s = kc & 7;
        const unsigned short* base = (kcl < 16) ? h0r : (h1r - 512);
        const unsigned short* p = base + rb0 * 512 + kcl * 32 + lqo;
        a_s[s][0] = ldA16(p);
        a_s[s][1] = ldA16(p + 8192);     // +16 rows
      };
      auto issueB = [&](int kc) {
        int kcl = kc < 32 ? kc : 31;
        int s = kc & 3;
        int ko = kcl * 32;
        b_s[s][0] = *(const s8v*)(wb + ko);
        b_s[s][1] = *(const s8v*)(wb + 524288 + ko);
        b_s[s][2] = *(const s8v*)(wb + 1048576 + ko);
        b_s[s][3] = *(const s8v*)(wb + 1572864 + ko);
      };
#pragma unroll
      for (int s = 0; s < 8; s++) issueA(s);
#pragma unroll
      for (int s = 0; s < 3; s++) issueB(s);
#pragma unroll
      for (int kc = 0; kc < 32; kc++) {
        s8v a0 = a_s[kc & 7][0], a1 = a_s[kc & 7][1];
#pragma unroll
        for (int g = 0; g < 4; g++) {
          acc[0][g] = __builtin_amdgcn_mfma_f32_16x16x32_bf16(a0, b_s[kc & 3][g], acc[0][g], 0, 0, 0);
          acc[1][g] = __builtin_amdgcn_mfma_f32_16x16x32_bf16(a1, b_s[kc & 3][g], acc[1][g], 0, 0, 0);
        }
        issueB(kc + 3);
        issueA(kc + 8);
      }
#pragma unroll
      for (int i = 0; i < 2; i++)
#pragma unroll
        for (int r = 0; r < 4; r++) {
          int mm = wave * 32 + i * 16 + lq * 4 + r;
          int idx = mm * 512 + j;
          float cprev = c1f[idx];
          float iv = sigm(acc[i][0][r] + bi);
          float ov = sigm(acc[i][1][r] + bo);
          float fv = sigm(acc[i][2][r] + bff);
          float cv = tanh_(acc[i][3][r] + bc);
          float cn = fv * cprev + iv * cv;
          float hn = ov * tanh_(cn);
          c1f[idx] = cn; h1f[idx] = hn;      // block-private: cached
          unsigned short hb = f2bf(hn);
          stU16(&h1w[idx], hb);              // cross-block: LLC
          stU16(&H1all[(size_t)(t * 128 + mm) * 512 + j], hb);
        }
      signal_inc(&FLAG(32 + t));
    }
  } else if (bid < 64) {
    // ======== stepA: z0 = Zx[t] + h0(t-1) @ W0h ; W0h slice warm in L2 ========
    int jt = bid - 32;
    int j = jt * 16 + lr;
    const unsigned short* wb = W0h_t + (size_t)j * 512 + lqo;   // gate g: +g*262144
    for (int t = 0; t < 32; t++) {
      // prefetch Zx for this step (precomputed, read-only: cached loads)
      float zx[2][4][4];
      const float* zb = Zx + (size_t)t * 262144 + j;
#pragma unroll
      for (int i = 0; i < 2; i++)
#pragma unroll
        for (int g = 0; g < 4; g++)
#pragma unroll
          for (int r = 0; r < 4; r++)
            zx[i][g][r] = zb[(wave * 32 + i * 16 + lq * 4 + r) * 2048 + g * 512];
      if (t >= 1) wait_ge(&FLAG(t - 1), 32);        // h0(t-1) ready
      if (t >= 2) wait_ge(&FLAG(32 + t - 2), 32);   // WAR on h0buf parity
      const unsigned short* h0r = (t & 1) ? h0b0 : h0b1;
      unsigned short* h0w = (t & 1) ? h0b1 : h0b0;
      f4v acc[2][4];
#pragma unroll
      for (int i = 0; i < 2; i++)
#pragma unroll
        for (int g = 0; g < 4; g++) acc[i][g] = zero;
      s8v a_s[8][2];
      s8v b_s[4][4];
      auto issueA = [&](int kc) {
        int kcl = kc < 16 ? kc : 15;
        int s = kc & 7;
        const unsigned short* p = h0r + rb0 * 512 + kcl * 32 + lqo;
        a_s[s][0] = ldA16(p);
        a_s[s][1] = ldA16(p + 8192);
      };
      auto issueB = [&](int kc) {
        int kcl = kc < 16 ? kc : 15;
        int s = kc & 3;
        int ko = kcl * 32;
        b_s[s][0] = *(const s8v*)(wb + ko);
        b_s[s][1] = *(const s8v*)(wb + 262144 + ko);
        b_s[s][2] = *(const s8v*)(wb + 524288 + ko);
        b_s[s][3] = *(const s8v*)(wb + 786432 + ko);
      };
#pragma unroll
      for (int s = 0; s < 8; s++) issueA(s);
#pragma unroll
      for (int s = 0; s < 3; s++) issueB(s);
#pragma unroll
      for (int kc = 0; kc < 16; kc++) {
        s8v a0 = a_s[kc & 7][0], a1 = a_s[kc & 7][1];
#pragma unroll
        for (int g = 0; g < 4; g++) {
          acc[0][g] = __builtin_amdgcn_mfma_f32_16x16x32_bf16(a0, b_s[kc & 3][g], acc[0][g], 0, 0, 0);
          acc[1][g] = __builtin_amdgcn_mfma_f32_16x16x32_bf16(a1, b_s[kc & 3][g], acc[1][g], 0, 0, 0);
        }
        issueB(kc + 3);
        issueA(kc + 8);
      }
#pragma unroll
      for (int i = 0; i < 2; i++)
#pragma unroll
        for (int r = 0; r < 4; r++) {
          int mm = wave * 32 + i * 16 + lq * 4 + r;
          int idx = mm * 512 + j;
          float cprev = c0f[idx];
          float iv = sigm(acc[i][0][r] + zx[i][0][r]);
          float ov = sigm(acc[i][1][r] + zx[i][1][r]);
          float fv = sigm(acc[i][2][r] + zx[i][2][r]);
          float cv = tanh_(acc[i][3][r] + zx[i][3][r]);
          float cn = fv * cprev + iv * cv;
          float hn = ov * tanh_(cn);
          c0f[idx] = cn; h0f[idx] = hn;      // block-private: cached
          stU16(&h0w[idx], f2bf(hn));        // cross-block: LLC
        }
      signal_inc(&FLAG(t));
    }
  } else {
    // ======== logits workers: out[(b*32+t)*10000+n] ========
    // H1all addresses are unique per t and only read after flagB(t): no XCD can
    // hold a stale copy -> plain cached reads are safe.
    int ww = bid - 64;
    int wm = (wave >> 1) * 64, wn = (wave & 1) * 64;
    int srow = tid >> 2, sofs = (tid & 3) * 8;
    int lastt = -1;
    for (int q = ww; q < 2528; q += 192) {   // 32 t x 79 tiles, t-major
      int t = q / 79, nb = q - t * 79;
      if (t != lastt) { wait_ge(&FLAG(32 + t), 32); lastt = t; }
      int n0 = nb * 128;
      const unsigned short* A = H1all + (size_t)t * 65536;
      int br0 = n0 + srow, br1 = br0 + 64;
      if (br0 > 9999) br0 = 9999;
      if (br1 > 9999) br1 = 9999;
      const unsigned short* Ag0 = A + srow * 512 + sofs;
      const unsigned short* Ag1 = A + (srow + 64) * 512 + sofs;
      const unsigned short* Bg0 = Wout_t + (size_t)br0 * 512 + sofs;
      const unsigned short* Bg1 = Wout_t + (size_t)br1 * 512 + sofs;
      f4v acc[4][4];
#pragma unroll
      for (int i = 0; i < 4; i++)
#pragma unroll
        for (int jj = 0; jj < 4; jj++) acc[i][jj] = zero;
      for (int k0 = 0; k0 < 512; k0 += 32) {
        glds16(Ag0 + k0, &As[tid * 8]);
        glds16(Ag1 + k0, &As[2048 + tid * 8]);
        glds16(Bg0 + k0, &Bs[tid * 8]);
        glds16(Bg1 + k0, &Bs[2048 + tid * 8]);
        __syncthreads();
        s8v af[4], bfr[4];
#pragma unroll
        for (int i = 0; i < 4; i++) af[i] = *(const s8v*)&As[(wm + i * 16 + lr) * 32 + lq * 8];
#pragma unroll
        for (int i = 0; i < 4; i++) bfr[i] = *(const s8v*)&Bs[(wn + i * 16 + lr) * 32 + lq * 8];
#pragma unroll
        for (int i = 0; i < 4; i++)
#pragma unroll
          for (int jj = 0; jj < 4; jj++)
            acc[i][jj] = __builtin_amdgcn_mfma_f32_16x16x32_bf16(af[i], bfr[jj], acc[i][jj], 0, 0, 0);
        __syncthreads();
      }
#pragma unroll
      for (int i = 0; i < 4; i++) {
#pragma unroll
        for (int jj = 0; jj < 4; jj++) {
          int nn = n0 + wn + jj * 16 + lr;
          if (nn >= 10000) continue;
#pragma unroll
          for (int r = 0; r < 4; r++) {
            int mm = wm + i * 16 + lq * 4 + r;   // = batch index b
            out[(size_t)(mm * 32 + t) * 10000 + nn] = acc[i][jj][r] + b_out[nn];
          }
        }
      }
    }
  }
}

// ---- final hidden writeout: out[40960000 + (l*128+b)*1024 + j] ----
__global__ void k_write_hidden(const float* __restrict__ h0f, const float* __restrict__ c0f,
                               const float* __restrict__ h1f, const float* __restrict__ c1f,
                               float* __restrict__ out) {
  int idx = blockIdx.x * 256 + threadIdx.x;  // 262144
  int l = idx >> 17, rem = idx & 131071, b = rem >> 10, j = rem & 1023;
  const float* hs = l ? h1f : h0f;
  const float* cs = l ? c1f : c0f;
  float v = (j < 512) ? hs[b * 512 + j] : cs[b * 512 + (j - 512)];
  out[40960000 + idx] = v;
}

extern "C" void kernel_launch(void* const* d_in, const int* in_sizes, int n_in,
                              void* d_out, int out_size, void* d_ws, size_t ws_size,
                              hipStream_t stream) {
  const float* cnn  = (const float*)d_in[0];
  const int*   tok  = (const int*)d_in[1];
  const float* chs  = (const float*)d_in[2];
  const float* emb  = (const float*)d_in[3];
  const float* W_in = (const float*)d_in[4];
  const float* b_in = (const float*)d_in[5];
  const float* W0   = (const float*)d_in[6];
  const float* b0   = (const float*)d_in[7];
  const float* W1   = (const float*)d_in[8];
  const float* b1   = (const float*)d_in[9];
  const float* W_out= (const float*)d_in[10];
  const float* b_out= (const float*)d_in[11];
  float* out = (float*)d_out;

  char* p = (char*)d_ws;
  auto alloc = [&](size_t bytes) { char* q = p; p += (bytes + 255) & ~(size_t)255; return q; };
  unsigned short* Win_t  = (unsigned short*)alloc((size_t)512 * 2048 * 2);
  unsigned short* W0e_t  = (unsigned short*)alloc((size_t)2048 * 512 * 2);
  unsigned short* W0m_t  = (unsigned short*)alloc((size_t)2048 * 512 * 2);
  unsigned short* W0h_t  = (unsigned short*)alloc((size_t)2048 * 512 * 2);
  unsigned short* W1_t   = (unsigned short*)alloc((size_t)2048 * 1024 * 2);
  unsigned short* Wout_t = (unsigned short*)alloc((size_t)10000 * 512 * 2);
  unsigned short* cnn_b  = (unsigned short*)alloc((size_t)128 * 2048 * 2);
  unsigned short* proc_b = (unsigned short*)alloc((size_t)128 * 512 * 2);
  float*          Cf     = (float*)alloc((size_t)128 * 2048 * 4);
  unsigned short* Xe     = (unsigned short*)alloc((size_t)4096 * 512 * 2);
  float*          Zx     = (float*)alloc((size_t)4096 * 2048 * 4);
  unsigned short* h0b0   = (unsigned short*)alloc(65536 * 2);
  unsigned short* h0b1   = (unsigned short*)alloc(65536 * 2);
  unsigned short* h1b0   = (unsigned short*)alloc(65536 * 2);
  unsigned short* h1b1   = (unsigned short*)alloc(65536 * 2);
  float*          h0f    = (float*)alloc(65536 * 4);
  float*          c0f    = (float*)alloc(65536 * 4);
  float*          h1f    = (float*)alloc(65536 * 4);
  float*          c1f    = (float*)alloc(65536 * 4);
  unsigned short* H1all  = (unsigned short*)alloc((size_t)4096 * 512 * 2);
  int*            flags  = (int*)alloc(1024 * 4);

  // 1) all pre-work in one launch (includes flag zeroing)
  k_prep<<<13713, dim3(32, 8), 0, stream>>>(W_in, W0, W1, W_out, cnn, emb, tok, chs,
                                            Win_t, W0e_t, W0m_t, W0h_t, W1_t, Wout_t,
                                            cnn_b, Xe, h0b1, h1b1, h0f, c0f, h1f, c1f, flags);
  // 2) proc = leaky(cnn @ W_in + b_in)
  k_gemm<0><<<dim3(4, 1), 256, 0, stream>>>(cnn_b, Win_t, b_in, nullptr, nullptr, proc_b,
                                            128, 512, 2048);
  // 3) Cf = proc @ W0[512:1024] + b0
  k_gemm<1><<<dim3(16, 1), 256, 0, stream>>>(proc_b, W0m_t, b0, nullptr, Cf, nullptr,
                                             128, 2048, 512);
  // 4) Zx[t*128+b] = emb_t @ W0[0:512] + Cf[b]
  k_gemm<2><<<dim3(16, 32), 256, 0, stream>>>(Xe, W0e_t, nullptr, Cf, Zx, nullptr,
                                              4096, 2048, 512);
  // 5) persistent recurrence + fused logits (fence-free)
  k_persist<<<256, 256, 0, stream>>>(W0h_t, W1_t, Zx, b1, h0b0, h0b1, h1b0, h1b1,
                                     h0f, c0f, h1f, c1f, H1all, Wout_t, b_out, out, flags);
  // 6) hidden-state writeout
  k_write_hidden<<<1024, 256, 0, stream>>>(h0f, c0f, h1f, c1f, out);
}

// Round 8
// 926.870 us; speedup vs baseline: 1.5860x; 1.5860x over previous
//
#include <hip/hip_runtime.h>

// ImageCaptionModel: B=128 T=32 V=10000 H=512 E=512 F=2048 NM=512
// Round 8: round-2 structure (verified 796us) + logits ride-along done right.
//   - phase: 256 blocks x 128 thr, gid = bid*2+wave, depth-8 pipelined bodies
//     (EXACT round-2 mapping/body; round-1's regression came from repacking
//     phase onto 64 CUs - not repeated here).
//   - logits(t-1): 157 extra 128-thr blocks per launch (128x64 tile, K=512)
//     reading H1all written by the PREVIOUS launch (kernel-boundary ordering).
//     They fill the ~254 idle CUs during the latency-bound phase.
//   - standalone logits GEMM removed (~85-95us saved).
//   - persistent/flag sync abandoned: rounds 3-7 proved >=20us/step for every
//     fence flavor on this 8-XCD part; kernel boundaries are the cheap sync.

typedef short s8v __attribute__((ext_vector_type(8)));   // 8 x bf16 bits
typedef float f4v __attribute__((ext_vector_type(4)));   // MFMA acc

__device__ __forceinline__ unsigned short f2bf(float f) {
  unsigned u = __float_as_uint(f);
  u += 0x7fffu + ((u >> 16) & 1u);          // round-to-nearest-even
  return (unsigned short)(u >> 16);
}
__device__ __forceinline__ float sigm(float x) { return 1.0f / (1.0f + __expf(-x)); }
__device__ __forceinline__ float tanh_(float x) { return 1.0f - 2.0f / (1.0f + __expf(2.0f * x)); }

__device__ __forceinline__ void glds16(const unsigned short* g, unsigned short* l) {
  __builtin_amdgcn_global_load_lds((const __attribute__((address_space(1))) void*)g,
                                   (__attribute__((address_space(3))) void*)l, 16, 0, 0);
}

// ---- fused pre-work: 6 transposes + cnn cvt + emb gather + state init ----
__global__ void k_prep(const float* __restrict__ W_in, const float* __restrict__ W0,
                       const float* __restrict__ W1, const float* __restrict__ W_out,
                       const float* __restrict__ cnn, const float* __restrict__ emb,
                       const int* __restrict__ tok, const float* __restrict__ chs,
                       unsigned short* __restrict__ Win_t, unsigned short* __restrict__ W0e_t,
                       unsigned short* __restrict__ W0m_t, unsigned short* __restrict__ W0h_t,
                       unsigned short* __restrict__ W1_t, unsigned short* __restrict__ Wout_t,
                       unsigned short* __restrict__ cnn_b, unsigned short* __restrict__ Xe,
                       unsigned short* __restrict__ h0b1, unsigned short* __restrict__ h1b1,
                       float* __restrict__ h0f, float* __restrict__ c0f,
                       float* __restrict__ h1f, float* __restrict__ c1f) {
  int blk = blockIdx.x;
  if (blk < 11152) {   // transpose jobs
    const float* src; unsigned short* dst; int R, C, bx, by;
    if (blk < 1024)      { src = W_in;             dst = Win_t;  R = 2048; C = 512;   bx = blk & 15; by = blk >> 4; }
    else if (blk < 2048) { int b2 = blk - 1024; src = W0;              dst = W0e_t;  R = 512;  C = 2048;  bx = b2 & 63; by = b2 >> 6; }
    else if (blk < 3072) { int b2 = blk - 2048; src = W0 + 512 * 2048; dst = W0m_t;  R = 512;  C = 2048;  bx = b2 & 63; by = b2 >> 6; }
    else if (blk < 4096) { int b2 = blk - 3072; src = W0 + 1024 * 2048; dst = W0h_t; R = 512;  C = 2048;  bx = b2 & 63; by = b2 >> 6; }
    else if (blk < 6144) { int b2 = blk - 4096; src = W1;              dst = W1_t;   R = 1024; C = 2048;  bx = b2 & 63; by = b2 >> 6; }
    else                 { int b2 = blk - 6144; src = W_out;           dst = Wout_t; R = 512;  C = 10000; bx = b2 % 313; by = b2 / 313; }
    __shared__ float tile[32][33];
    int c0 = bx * 32, r0 = by * 32;
    int tx = threadIdx.x, ty = threadIdx.y;
#pragma unroll
    for (int i = 0; i < 4; i++) {
      int r = r0 + ty + i * 8, c = c0 + tx;
      if (r < R && c < C) tile[ty + i * 8][tx] = src[(size_t)r * C + c];
    }
    __syncthreads();
#pragma unroll
    for (int i = 0; i < 4; i++) {
      int c = c0 + ty + i * 8, r = r0 + tx;
      if (r < R && c < C) dst[(size_t)c * R + r] = f2bf(tile[tx][ty + i * 8]);
    }
    return;
  }
  int ft = threadIdx.y * 32 + threadIdx.x;
  if (blk < 11408) {        // cnn fp32 -> bf16 (65536 float4s)
    int i = (blk - 11152) * 256 + ft;
    float4 v = ((const float4*)cnn)[i];
    ushort4 p; p.x = f2bf(v.x); p.y = f2bf(v.y); p.z = f2bf(v.z); p.w = f2bf(v.w);
    ((ushort4*)cnn_b)[i] = p;
  } else if (blk < 13456) { // embedding gather (524288 float4s)
    int i = (blk - 11408) * 256 + ft;
    int r = i >> 7, k4 = (i & 127) * 4;
    int b = r & 127, t = r >> 7;
    int tk = tok[b * 32 + t];
    float4 v = *(const float4*)(emb + (size_t)tk * 512 + k4);
    ushort4 p; p.x = f2bf(v.x); p.y = f2bf(v.y); p.z = f2bf(v.z); p.w = f2bf(v.w);
    ((ushort4*)Xe)[i] = p;
  } else {                  // init h/c state (65536)
    int i = (blk - 13456) * 256 + ft;
    int b = i >> 9, jj = i & 511;
    float h0 = chs[b * 1024 + jj], c0v = chs[b * 1024 + 512 + jj];
    float h1 = chs[131072 + b * 1024 + jj], c1v = chs[131072 + b * 1024 + 512 + jj];
    h0f[i] = h0; c0f[i] = c0v; h1f[i] = h1; c1f[i] = c1v;
    h0b1[i] = f2bf(h0); h1b1[i] = f2bf(h1);
  }
}

// ---- generic 128x128-tile GEMM (pre-work): C = A[M][K] * Bt[N][K]^T (+epilogue)
// MODE 0: proc = leaky(acc+bias) -> outB ; MODE 1: Cf = acc+bias -> outF
// MODE 2: Zx = acc + add128[m&127][n] -> outF
template <int MODE>
__global__ __launch_bounds__(256, 2)
void k_gemm(const unsigned short* __restrict__ A, const unsigned short* __restrict__ Bt,
            const float* __restrict__ bias, const float* __restrict__ add128,
            float* __restrict__ outF, unsigned short* __restrict__ outB,
            int M, int N, int K) {
  __shared__ unsigned short As[4096];
  __shared__ unsigned short Bs[4096];
  int tid = threadIdx.x;
  int wave = tid >> 6, lane = tid & 63;
  int lr = lane & 15, lq = lane >> 4;
  int wm = (wave >> 1) * 64, wn = (wave & 1) * 64;
  int m0 = blockIdx.y * 128, n0 = blockIdx.x * 128;

  f4v acc[4][4];
  f4v zero = {0.0f, 0.0f, 0.0f, 0.0f};
#pragma unroll
  for (int i = 0; i < 4; i++)
#pragma unroll
    for (int j = 0; j < 4; j++) acc[i][j] = zero;

  int srow = tid >> 2, sofs = (tid & 3) * 8;
  int ar0 = m0 + srow, ar1 = ar0 + 64;
  int br0 = n0 + srow, br1 = br0 + 64;
  if (br0 >= N) br0 = N - 1;
  if (br1 >= N) br1 = N - 1;
  const unsigned short* Ag0 = A + (size_t)ar0 * K + sofs;
  const unsigned short* Ag1 = A + (size_t)ar1 * K + sofs;
  const unsigned short* Bg0 = Bt + (size_t)br0 * K + sofs;
  const unsigned short* Bg1 = Bt + (size_t)br1 * K + sofs;

  for (int k0 = 0; k0 < K; k0 += 32) {
    glds16(Ag0 + k0, &As[tid * 8]);
    glds16(Ag1 + k0, &As[2048 + tid * 8]);
    glds16(Bg0 + k0, &Bs[tid * 8]);
    glds16(Bg1 + k0, &Bs[2048 + tid * 8]);
    __syncthreads();
    s8v af[4], bfr[4];
#pragma unroll
    for (int i = 0; i < 4; i++) af[i] = *(const s8v*)&As[(wm + i * 16 + lr) * 32 + lq * 8];
#pragma unroll
    for (int i = 0; i < 4; i++) bfr[i] = *(const s8v*)&Bs[(wn + i * 16 + lr) * 32 + lq * 8];
#pragma unroll
    for (int i = 0; i < 4; i++)
#pragma unroll
      for (int j = 0; j < 4; j++)
        acc[i][j] = __builtin_amdgcn_mfma_f32_16x16x32_bf16(af[i], bfr[j], acc[i][j], 0, 0, 0);
    __syncthreads();
  }

#pragma unroll
  for (int i = 0; i < 4; i++) {
#pragma unroll
    for (int j = 0; j < 4; j++) {
      int nn = n0 + wn + j * 16 + lr;
      if (nn >= N) continue;
#pragma unroll
      for (int r = 0; r < 4; r++) {
        int mm = m0 + wm + i * 16 + lq * 4 + r;
        float v = acc[i][j][r];
        if (MODE == 0) {
          v += bias[nn];
          v = v > 0.0f ? v : 0.01f * v;
          outB[(size_t)mm * N + nn] = f2bf(v);
        } else if (MODE == 1) {
          v += bias[nn];
          outF[(size_t)mm * N + nn] = v;
        } else {
          v += add128[(size_t)(mm & 127) * N + nn];
          outF[(size_t)mm * N + nn] = v;
        }
      }
    }
  }
}

// ---- fused recurrence phase + logits ride-along ----
// blocks [0, nPB):   phase wave-jobs, gid = bid*2 + wave (EXACT round-2 layout)
//   stepB(tB): z1=[h0n|h1]@W1+b1 -> h1n,c1n (+H1all)
//   stepA(tA): z0=Zx[tA]+h0@W0h  -> h0n,c0n
// blocks [nPB, ...): logits tile (128 x 64, K=512) for step tL, reading H1all
//   written by the PREVIOUS launch -> out[(b*32+tL)*10000 + n]
__global__ __launch_bounds__(128)
void k_phase(const unsigned short* __restrict__ W0h_t, const unsigned short* __restrict__ W1_t,
             const float* __restrict__ Zx, const float* __restrict__ b1,
             unsigned short* __restrict__ h0b0, unsigned short* __restrict__ h0b1,
             unsigned short* __restrict__ h1b0, unsigned short* __restrict__ h1b1,
             float* __restrict__ h0f, float* __restrict__ c0f,
             float* __restrict__ h1f, float* __restrict__ c1f,
             unsigned short* __restrict__ H1all,
             const unsigned short* __restrict__ Wout_t, const float* __restrict__ b_out,
             float* __restrict__ out,
             int tB, int doB, int tA, int doA, int tL, int doL, int nPB) {
  int tid = threadIdx.x;
  int wave = tid >> 6, lane = tid & 63;
  int lr = lane & 15, lq = lane >> 4;
  f4v zero = {0.0f, 0.0f, 0.0f, 0.0f};

  if ((int)blockIdx.x >= nPB) {
    // ---------------- logits tile: 128 rows (all b) x 64 cols, 2 waves -------
    if (!doL) return;
    __shared__ __align__(16) unsigned short As[4096];  // 128 x 32
    __shared__ __align__(16) unsigned short Bs[2048];  // 64 x 32
    int lb = (int)blockIdx.x - nPB;           // 0..156
    int n0 = lb * 64;
    const unsigned short* A = H1all + (size_t)tL * 65536;
    int srow = tid >> 2, sofs = (tid & 3) * 8;

    f4v acc[4][4];
#pragma unroll
    for (int i = 0; i < 4; i++)
#pragma unroll
      for (int j = 0; j < 4; j++) acc[i][j] = zero;

    // clamp ragged B rows (masked in epilogue)
    int br0 = n0 + srow;       if (br0 > 9999) br0 = 9999;
    int br1 = n0 + 32 + srow;  if (br1 > 9999) br1 = 9999;
    const unsigned short* Bg0 = Wout_t + (size_t)br0 * 512 + sofs;
    const unsigned short* Bg1 = Wout_t + (size_t)br1 * 512 + sofs;

    for (int k0 = 0; k0 < 512; k0 += 32) {
#pragma unroll
      for (int c = 0; c < 4; c++)   // A: rows c*32 + srow
        glds16(A + (size_t)(c * 32 + srow) * 512 + sofs + k0, &As[c * 1024 + tid * 8]);
      glds16(Bg0 + k0, &Bs[tid * 8]);
      glds16(Bg1 + k0, &Bs[1024 + tid * 8]);
      __syncthreads();
      // As[(r>>5)*1024 + ((r>>4)&1)*512 + (r&15)*32 + k] holds A[r][k0+k]
      s8v af[4], bfr[4];
#pragma unroll
      for (int i = 0; i < 4; i++)
        af[i] = *(const s8v*)&As[wave * 2048 + (i >> 1) * 1024 + (i & 1) * 512 + lr * 32 + lq * 8];
#pragma unroll
      for (int j = 0; j < 4; j++)
        bfr[j] = *(const s8v*)&Bs[(j >> 1) * 1024 + (j & 1) * 512 + lr * 32 + lq * 8];
#pragma unroll
      for (int i = 0; i < 4; i++)
#pragma unroll
        for (int j = 0; j < 4; j++)
          acc[i][j] = __builtin_amdgcn_mfma_f32_16x16x32_bf16(af[i], bfr[j], acc[i][j], 0, 0, 0);
      __syncthreads();
    }

#pragma unroll
    for (int i = 0; i < 4; i++) {
#pragma unroll
      for (int j = 0; j < 4; j++) {
        int nn = n0 + j * 16 + lr;
        if (nn >= 10000) continue;
#pragma unroll
        for (int r = 0; r < 4; r++) {
          int b = wave * 64 + i * 16 + lq * 4 + r;   // batch index
          out[(size_t)(b * 32 + tL) * 10000 + nn] = acc[i][j][r] + b_out[nn];
        }
      }
    }
    return;
  }

  // ---------------- phase wave-jobs (round-2 body, unchanged) ----------------
  int gid = (int)blockIdx.x * 2 + wave;     // 512 wave-jobs
  bool isB = gid < 256;
  if (isB && !doB) return;
  if (!isB && !doA) return;
  int id = gid & 255;
  int mt = id >> 5, jt = id & 31;      // 8 m-tiles x 32 j-tiles
  int m = mt * 16 + lr;                // A-operand row = lane&15
  int lqo = lq * 8;
  f4v acc[4] = {zero, zero, zero, zero};

  if (isB) {
    const unsigned short* h0r = (tB & 1) ? h0b1 : h0b0;   // h0buf[tB&1]
    const unsigned short* h1r = (tB & 1) ? h1b0 : h1b1;   // h1buf[(tB+1)&1]
    unsigned short* h1w = (tB & 1) ? h1b1 : h1b0;         // h1buf[tB&1]

    const unsigned short* pA0 = h0r + m * 512 + lqo;        // K in [0,512)
    const unsigned short* pA1 = h1r + m * 512 + lqo - 512;  // K in [512,1024)
    const unsigned short* wb  = W1_t + (size_t)(jt * 16 + lr) * 1024 + lqo;

    s8v a_s[8];
    s8v b_s[8][4];
    auto issueB = [&](int kc, int slot) {
      int kcl = kc < 32 ? kc : 31;     // clamp: duplicate last-iter loads, unused
      int ko = kcl * 32;
      const unsigned short* ap = (ko + lqo < 512) ? (pA0 + ko) : (pA1 + ko);
      a_s[slot] = *(const s8v*)ap;
      b_s[slot][0] = *(const s8v*)(wb + ko);
      b_s[slot][1] = *(const s8v*)(wb + 524288 + ko);      // +512*1024
      b_s[slot][2] = *(const s8v*)(wb + 1048576 + ko);
      b_s[slot][3] = *(const s8v*)(wb + 1572864 + ko);
    };
#pragma unroll
    for (int s = 0; s < 8; s++) issueB(s, s);
#pragma unroll
    for (int kc = 0; kc < 32; kc++) {  // fully unrolled: slot indices static
      int slot = kc & 7;
      s8v a = a_s[slot];
      acc[0] = __builtin_amdgcn_mfma_f32_16x16x32_bf16(a, b_s[slot][0], acc[0], 0, 0, 0);
      acc[1] = __builtin_amdgcn_mfma_f32_16x16x32_bf16(a, b_s[slot][1], acc[1], 0, 0, 0);
      acc[2] = __builtin_amdgcn_mfma_f32_16x16x32_bf16(a, b_s[slot][2], acc[2], 0, 0, 0);
      acc[3] = __builtin_amdgcn_mfma_f32_16x16x32_bf16(a, b_s[slot][3], acc[3], 0, 0, 0);
      issueB(kc + 8, slot);
    }

    int j = jt * 16 + lr;
    float bi = b1[j], bo = b1[512 + j], bff = b1[1024 + j], bc = b1[1536 + j];
#pragma unroll
    for (int r = 0; r < 4; r++) {
      int mm = mt * 16 + lq * 4 + r;
      int idx = mm * 512 + j;
      float cprev = c1f[idx];
      float iv = sigm(acc[0][r] + bi);
      float ov = sigm(acc[1][r] + bo);
      float fv = sigm(acc[2][r] + bff);
      float cv = tanh_(acc[3][r] + bc);
      float cn = fv * cprev + iv * cv;
      float hn = ov * tanh_(cn);
      c1f[idx] = cn; h1f[idx] = hn;
      unsigned short hb = f2bf(hn);
      h1w[idx] = hb;
      H1all[(size_t)(tB * 128 + mm) * 512 + j] = hb;
    }
  } else {
    const unsigned short* h0r = (tA & 1) ? h0b0 : h0b1;   // h0buf[(tA+1)&1]
    unsigned short* h0w = (tA & 1) ? h0b1 : h0b0;         // h0buf[tA&1]

    const unsigned short* pA = h0r + m * 512 + lqo;
    const unsigned short* wb = W0h_t + (size_t)(jt * 16 + lr) * 512 + lqo;

    s8v a_s[8];
    s8v b_s[8][4];
    auto issueA = [&](int kc, int slot) {
      int kcl = kc < 16 ? kc : 15;
      int ko = kcl * 32;
      a_s[slot] = *(const s8v*)(pA + ko);
      b_s[slot][0] = *(const s8v*)(wb + ko);
      b_s[slot][1] = *(const s8v*)(wb + 262144 + ko);      // +512*512
      b_s[slot][2] = *(const s8v*)(wb + 524288 + ko);
      b_s[slot][3] = *(const s8v*)(wb + 786432 + ko);
    };
#pragma unroll
    for (int s = 0; s < 8; s++) issueA(s, s);
#pragma unroll
    for (int kc = 0; kc < 16; kc++) {  // fully unrolled: slot indices static
      int slot = kc & 7;
      s8v a = a_s[slot];
      acc[0] = __builtin_amdgcn_mfma_f32_16x16x32_bf16(a, b_s[slot][0], acc[0], 0, 0, 0);
      acc[1] = __builtin_amdgcn_mfma_f32_16x16x32_bf16(a, b_s[slot][1], acc[1], 0, 0, 0);
      acc[2] = __builtin_amdgcn_mfma_f32_16x16x32_bf16(a, b_s[slot][2], acc[2], 0, 0, 0);
      acc[3] = __builtin_amdgcn_mfma_f32_16x16x32_bf16(a, b_s[slot][3], acc[3], 0, 0, 0);
      issueA(kc + 8, slot);
    }

    int j = jt * 16 + lr;
    const float* zrow = Zx + (size_t)tA * 128 * 2048;
#pragma unroll
    for (int r = 0; r < 4; r++) {
      int mm = mt * 16 + lq * 4 + r;
      int idx = mm * 512 + j;
      float cprev = c0f[idx];
      float iv = sigm(acc[0][r] + zrow[mm * 2048 + j]);
      float ov = sigm(acc[1][r] + zrow[mm * 2048 + 512 + j]);
      float fv = sigm(acc[2][r] + zrow[mm * 2048 + 1024 + j]);
      float cv = tanh_(acc[3][r] + zrow[mm * 2048 + 1536 + j]);
      float cn = fv * cprev + iv * cv;
      float hn = ov * tanh_(cn);
      c0f[idx] = cn; h0f[idx] = hn;
      h0w[idx] = f2bf(hn);
    }
  }
}

// ---- final hidden writeout: out[40960000 + (l*128+b)*1024 + j] ----
__global__ void k_write_hidden(const float* __restrict__ h0f, const float* __restrict__ c0f,
                               const float* __restrict__ h1f, const float* __restrict__ c1f,
                               float* __restrict__ out) {
  int idx = blockIdx.x * 256 + threadIdx.x;  // 262144
  int l = idx >> 17, rem = idx & 131071, b = rem >> 10, j = rem & 1023;
  const float* hs = l ? h1f : h0f;
  const float* cs = l ? c1f : c0f;
  float v = (j < 512) ? hs[b * 512 + j] : cs[b * 512 + (j - 512)];
  out[40960000 + idx] = v;
}

extern "C" void kernel_launch(void* const* d_in, const int* in_sizes, int n_in,
                              void* d_out, int out_size, void* d_ws, size_t ws_size,
                              hipStream_t stream) {
  const float* cnn  = (const float*)d_in[0];
  const int*   tok  = (const int*)d_in[1];
  const float* chs  = (const float*)d_in[2];
  const float* emb  = (const float*)d_in[3];
  const float* W_in = (const float*)d_in[4];
  const float* b_in = (const float*)d_in[5];
  const float* W0   = (const float*)d_in[6];
  const float* b0   = (const float*)d_in[7];
  const float* W1   = (const float*)d_in[8];
  const float* b1   = (const float*)d_in[9];
  const float* W_out= (const float*)d_in[10];
  const float* b_out= (const float*)d_in[11];
  float* out = (float*)d_out;

  char* p = (char*)d_ws;
  auto alloc = [&](size_t bytes) { char* q = p; p += (bytes + 255) & ~(size_t)255; return q; };
  unsigned short* Win_t  = (unsigned short*)alloc((size_t)512 * 2048 * 2);
  unsigned short* W0e_t  = (unsigned short*)alloc((size_t)2048 * 512 * 2);
  unsigned short* W0m_t  = (unsigned short*)alloc((size_t)2048 * 512 * 2);
  unsigned short* W0h_t  = (unsigned short*)alloc((size_t)2048 * 512 * 2);
  unsigned short* W1_t   = (unsigned short*)alloc((size_t)2048 * 1024 * 2);
  unsigned short* Wout_t = (unsigned short*)alloc((size_t)10000 * 512 * 2);
  unsigned short* cnn_b  = (unsigned short*)alloc((size_t)128 * 2048 * 2);
  unsigned short* proc_b = (unsigned short*)alloc((size_t)128 * 512 * 2);
  float*          Cf     = (float*)alloc((size_t)128 * 2048 * 4);
  unsigned short* Xe     = (unsigned short*)alloc((size_t)4096 * 512 * 2);
  float*          Zx     = (float*)alloc((size_t)4096 * 2048 * 4);
  unsigned short* h0b0   = (unsigned short*)alloc(65536 * 2);
  unsigned short* h0b1   = (unsigned short*)alloc(65536 * 2);
  unsigned short* h1b0   = (unsigned short*)alloc(65536 * 2);
  unsigned short* h1b1   = (unsigned short*)alloc(65536 * 2);
  float*          h0f    = (float*)alloc(65536 * 4);
  float*          c0f    = (float*)alloc(65536 * 4);
  float*          h1f    = (float*)alloc(65536 * 4);
  float*          c1f    = (float*)alloc(65536 * 4);
  unsigned short* H1all  = (unsigned short*)alloc((size_t)4096 * 512 * 2);

  // 1) all pre-work in one launch
  k_prep<<<13712, dim3(32, 8), 0, stream>>>(W_in, W0, W1, W_out, cnn, emb, tok, chs,
                                            Win_t, W0e_t, W0m_t, W0h_t, W1_t, Wout_t,
                                            cnn_b, Xe, h0b1, h1b1, h0f, c0f, h1f, c1f);
  // 2) proc = leaky(cnn @ W_in + b_in)
  k_gemm<0><<<dim3(4, 1), 256, 0, stream>>>(cnn_b, Win_t, b_in, nullptr, nullptr, proc_b,
                                            128, 512, 2048);
  // 3) Cf = proc @ W0[512:1024] + b0
  k_gemm<1><<<dim3(16, 1), 256, 0, stream>>>(proc_b, W0m_t, b0, nullptr, Cf, nullptr,
                                             128, 2048, 512);
  // 4) Zx[t*128+b] = emb_t @ W0[0:512] + Cf[b]
  k_gemm<2><<<dim3(16, 32), 256, 0, stream>>>(Xe, W0e_t, nullptr, Cf, Zx, nullptr,
                                              4096, 2048, 512);

  // 5) recurrence with logits ride-along:
  //    launch 0:   stepA(0)
  //    launch t+1: stepB(t) || stepA(t+1) || logits(t-1)
  //    final:      logits(31)
  const int NPB = 256;  // phase blocks (round-2 layout: 2 wave-jobs each)
  k_phase<<<NPB, 128, 0, stream>>>(W0h_t, W1_t, Zx, b1, h0b0, h0b1, h1b0, h1b1,
                                   h0f, c0f, h1f, c1f, H1all, Wout_t, b_out, out,
                                   0, 0, 0, 1, 0, 0, NPB);
  for (int t = 0; t < 32; t++) {
    int doL = (t >= 1) ? 1 : 0;
    int grid = NPB + (doL ? 157 : 0);
    k_phase<<<grid, 128, 0, stream>>>(W0h_t, W1_t, Zx, b1, h0b0, h0b1, h1b0, h1b1,
                                      h0f, c0f, h1f, c1f, H1all, Wout_t, b_out, out,
                                      t, 1, t + 1, (t < 31) ? 1 : 0, t - 1, doL, NPB);
  }
  k_phase<<<157, 128, 0, stream>>>(W0h_t, W1_t, Zx, b1, h0b0, h0b1, h1b0, h1b1,
                                   h0f, c0f, h1f, c1f, H1all, Wout_t, b_out, out,
                                   0, 0, 0, 0, 31, 1, 0);

  // 6) hidden-state writeout
  k_write_hidden<<<1024, 256, 0, stream>>>(h0f, c0f, h1f, c1f, out);
}